// Round 14
// baseline (332.666 us; speedup 1.0000x reference)
//
#include <hip/hip_runtime.h>
#include <hip/hip_bf16.h>
#include <math.h>

#define DMODEL 1024
#define NSEQ   2048
#define NBATCH 2
#define NHEADS 16
#define DHEAD  64
#define DFF    4096
#define MROWS  (NBATCH*NSEQ)
#define QKVLD  3072   // fused qkv row stride

typedef __attribute__((ext_vector_type(8))) short bf16x8;
typedef __attribute__((ext_vector_type(4))) float f32x4;

static __device__ __forceinline__ ushort f2b(float f) {
    return __builtin_bit_cast(ushort, (__bf16)f);
}

static __device__ __forceinline__ f32x4 mfma16(bf16x8 a, bf16x8 b, f32x4 c) {
    return __builtin_amdgcn_mfma_f32_16x16x32_bf16(a, b, c, 0, 0, 0);
}

static __device__ __forceinline__ void gload_lds16(const void* g, void* lds) {
    __builtin_amdgcn_global_load_lds((const __attribute__((address_space(1))) void*)g,
                                     (__attribute__((address_space(3))) void*)lds,
                                     16, 0, 0);
}

// ---------------- fused prep: 6 weight cast+transposes (LDS transpose) + bias concat + LN1 ----------------
static __device__ __forceinline__ void cast_tile_lds(const float* __restrict__ W,
                                                     ushort* __restrict__ Wt,
                                                     int K, int Nn, int bx, int by, int t,
                                                     float (*lds)[65])
{
    const int n0 = bx * 64;
    const int k0 = by * 64;
#pragma unroll
    for (int r = 0; r < 4; ++r) {
        const int kr = (t >> 4) + r * 16;
        const int nc = (t & 15) * 4;
        const float4 v = *(const float4*)(W + (long)(k0 + kr) * Nn + n0 + nc);
        lds[kr][nc] = v.x; lds[kr][nc + 1] = v.y; lds[kr][nc + 2] = v.z; lds[kr][nc + 3] = v.w;
    }
    __syncthreads();
    const int n  = t >> 2;            // 0..63 output row
    const int kc = (t & 3) * 16;      // 16 k per lane; 4 lanes cover 128B contiguous
    ushort tmp[16];
#pragma unroll
    for (int i = 0; i < 16; ++i) tmp[i] = f2b(lds[kc + i][n]);
    *(uint4*)(Wt + (long)(n0 + n) * K + k0 + kc)     = *(const uint4*)tmp;
    *(uint4*)(Wt + (long)(n0 + n) * K + k0 + kc + 8) = *(const uint4*)(tmp + 8);
}

__global__ __launch_bounds__(256) void prep(const float* __restrict__ wq,
                                            const float* __restrict__ wk,
                                            const float* __restrict__ wv,
                                            const float* __restrict__ wo,
                                            const float* __restrict__ w1,
                                            const float* __restrict__ w2,
                                            const float* __restrict__ bq,
                                            const float* __restrict__ bk,
                                            const float* __restrict__ bv,
                                            const float* __restrict__ x,
                                            const float* __restrict__ ln1g,
                                            const float* __restrict__ ln1b,
                                            ushort* __restrict__ wqkv_t,
                                            ushort* __restrict__ wo_t,
                                            ushort* __restrict__ w1_t,
                                            ushort* __restrict__ w2_t,
                                            float* __restrict__ bqkv,
                                            ushort* __restrict__ normed)
{
    __shared__ float red[4];
    __shared__ float tl[64][65];
    const int id  = blockIdx.x;
    const int tid = threadIdx.x;

    if (id < 256) {                       // wq: 16x16 tiles
        cast_tile_lds(wq, wqkv_t, 1024, 1024, id & 15, id >> 4, tid, tl);
    } else if (id < 512) {
        const int i2 = id - 256;
        cast_tile_lds(wk, wqkv_t + 1024 * 1024, 1024, 1024, i2 & 15, i2 >> 4, tid, tl);
    } else if (id < 768) {
        const int i2 = id - 512;
        cast_tile_lds(wv, wqkv_t + 2048 * 1024, 1024, 1024, i2 & 15, i2 >> 4, tid, tl);
    } else if (id < 1024) {
        const int i2 = id - 768;
        cast_tile_lds(wo, wo_t, 1024, 1024, i2 & 15, i2 >> 4, tid, tl);
    } else if (id < 2048) {               // w1: [1024][4096] -> Wt[4096][1024]
        const int i2 = id - 1024;
        cast_tile_lds(w1, w1_t, 1024, 4096, i2 & 63, i2 >> 6, tid, tl);
    } else if (id < 3072) {               // w2: [4096][1024] -> Wt[1024][4096]
        const int i2 = id - 2048;
        cast_tile_lds(w2, w2_t, 4096, 1024, i2 & 15, i2 >> 4, tid, tl);
    } else if (id < 3088) {
        const int t = (id - 3072) * 256 + tid;
        float v = 0.0f;
        if (t < 1024)      v = bq[t];
        else if (t < 2048) v = bk[t - 1024];
        else if (t < 3072) v = bv[t - 2048];
        bqkv[t] = v;
    } else {
        const int row = id - 3088;
        const float4 v = ((const float4*)(x + (long)row * DMODEL))[tid];
        float s = v.x + v.y + v.z + v.w;
#pragma unroll
        for (int o = 32; o; o >>= 1) s += __shfl_down(s, o, 64);
        if ((tid & 63) == 0) red[tid >> 6] = s;
        __syncthreads();
        const float mu = (red[0] + red[1] + red[2] + red[3]) * (1.0f / DMODEL);
        __syncthreads();
        const float d0 = v.x - mu, d1 = v.y - mu, d2 = v.z - mu, d3 = v.w - mu;
        float s2 = d0*d0 + d1*d1 + d2*d2 + d3*d3;
#pragma unroll
        for (int o = 32; o; o >>= 1) s2 += __shfl_down(s2, o, 64);
        if ((tid & 63) == 0) red[tid >> 6] = s2;
        __syncthreads();
        const float inv = rsqrtf((red[0] + red[1] + red[2] + red[3]) * (1.0f / DMODEL) + 1e-5f);
        const float4 gg = ((const float4*)ln1g)[tid];
        const float4 bv4 = ((const float4*)ln1b)[tid];
        ushort4 o4;
        o4.x = f2b(d0 * inv * gg.x + bv4.x);
        o4.y = f2b(d1 * inv * gg.y + bv4.y);
        o4.z = f2b(d2 * inv * gg.z + bv4.z);
        o4.w = f2b(d3 * inv * gg.w + bv4.w);
        ((ushort4*)(normed + (long)row * DMODEL))[tid] = o4;
    }
}

// ---------------- LayerNorm (standalone, used for LN2) ----------------
__global__ __launch_bounds__(256) void ln_kernel(const float* __restrict__ x,
                                                 const float* __restrict__ g,
                                                 const float* __restrict__ bb,
                                                 ushort* __restrict__ out)
{
    const int row = blockIdx.x;
    const int tid = threadIdx.x;
    const float4 v = ((const float4*)(x + (long)row * DMODEL))[tid];
    float s = v.x + v.y + v.z + v.w;
#pragma unroll
    for (int o = 32; o; o >>= 1) s += __shfl_down(s, o, 64);
    __shared__ float red[4];
    if ((tid & 63) == 0) red[tid >> 6] = s;
    __syncthreads();
    const float mu = (red[0] + red[1] + red[2] + red[3]) * (1.0f / DMODEL);
    __syncthreads();
    const float d0 = v.x - mu, d1 = v.y - mu, d2 = v.z - mu, d3 = v.w - mu;
    float s2 = d0*d0 + d1*d1 + d2*d2 + d3*d3;
#pragma unroll
    for (int o = 32; o; o >>= 1) s2 += __shfl_down(s2, o, 64);
    if ((tid & 63) == 0) red[tid >> 6] = s2;
    __syncthreads();
    const float inv = rsqrtf((red[0] + red[1] + red[2] + red[3]) * (1.0f / DMODEL) + 1e-5f);
    const float4 gg = ((const float4*)g)[tid];
    const float4 bv = ((const float4*)bb)[tid];
    ushort4 o4;
    o4.x = f2b(d0 * inv * gg.x + bv.x);
    o4.y = f2b(d1 * inv * gg.y + bv.y);
    o4.z = f2b(d2 * inv * gg.z + bv.z);
    o4.w = f2b(d3 * inv * gg.w + bv.w);
    ((ushort4*)(out + (long)row * DMODEL))[tid] = o4;
}

// ---------------- deep-pipelined 128x256 GEMM, 8 waves, BK=32, 3 LDS buffers, depth-2 ----------------
template<bool GELU>
__global__ __launch_bounds__(512, 2) void gemm128(const ushort* __restrict__ A, int lda,
                                                  const ushort* __restrict__ Bt, int ldb,
                                                  const float* __restrict__ bias,
                                                  ushort* __restrict__ C, int ldc, int K)
{
    extern __shared__ char smem[];
    const int tid  = threadIdx.x;
    const int lane = tid & 63;
    const int w    = tid >> 6;
    const int wm   = w >> 2;                // 0..1  (M half, 64 rows each)
    const int wn   = w & 3;                 // 0..3  (N quarter)
    const long row0 = (long)blockIdx.x * 128;
    const long col0 = (long)blockIdx.y * 256;

    const int srow = tid >> 2;              // 0..127
    const int scol = (((tid & 3) ^ ((srow >> 1) & 3))) * 8;   // inverse-swizzled source slot
    const ushort* Ag = A  + (row0 + srow) * (long)lda + scol;
    const ushort* Bg = Bt + (col0 + srow) * (long)ldb + scol;

#define STAGE_A1(buf, k0)                                                                  \
    gload_lds16(Ag + (k0), smem + (buf) * 8192 + w * 1024)
#define STAGE_B1(buf, k0)                                                                  \
    do {                                                                                   \
        gload_lds16(Bg + (k0),                   smem + 24576 + (buf) * 16384 + w * 1024); \
        gload_lds16(Bg + 128 * (long)ldb + (k0), smem + 24576 + (buf) * 16384 + 8192 + w * 1024); \
    } while (0)

    const f32x4 zero = {0.f, 0.f, 0.f, 0.f};
    f32x4 acc[4][4];
#pragma unroll
    for (int m = 0; m < 4; ++m)
#pragma unroll
        for (int j = 0; j < 4; ++j) acc[m][j] = zero;

    const int NT = K >> 5;
    STAGE_A1(0, 0);  STAGE_B1(0, 0);
    STAGE_A1(1, 32); STAGE_B1(1, 32);

    const int mrow = lane & 15;
    const int xsl  = (((lane >> 4) ^ ((mrow >> 1) & 3))) * 8;  // swizzled read slot
    const int abase = (wm * 64 + mrow) * 32 + xsl;
    const int bbase = (wn * 64 + mrow) * 32 + xsl;

    for (int t = 0; t < NT; ++t) {
        if (t == NT - 1) asm volatile("s_waitcnt vmcnt(0)" ::: "memory");
        else             asm volatile("s_waitcnt vmcnt(3)" ::: "memory");
        __builtin_amdgcn_sched_barrier(0);
        __builtin_amdgcn_s_barrier();
        __builtin_amdgcn_sched_barrier(0);

        const int cb = t % 3;
        const ushort* Abase = (const ushort*)(smem + cb * 8192);
        const ushort* Bbase = (const ushort*)(smem + 24576 + cb * 16384);

        bf16x8 bfr[4], afr[2];
#pragma unroll
        for (int ni = 0; ni < 4; ++ni)
            bfr[ni] = *(const bf16x8*)&Bbase[bbase + ni * 512];
#pragma unroll
        for (int mi = 0; mi < 2; ++mi)
            afr[mi] = *(const bf16x8*)&Abase[abase + mi * 512];
        if (t + 2 < NT) STAGE_A1((t + 2) % 3, (t + 2) * 32);
        __builtin_amdgcn_s_setprio(1);
#pragma unroll
        for (int mi = 0; mi < 2; ++mi)
#pragma unroll
            for (int ni = 0; ni < 4; ++ni)
                acc[mi][ni] = mfma16(afr[mi], bfr[ni], acc[mi][ni]);
        __builtin_amdgcn_s_setprio(0);

#pragma unroll
        for (int mi = 0; mi < 2; ++mi)
            afr[mi] = *(const bf16x8*)&Abase[abase + (mi + 2) * 512];
        if (t + 2 < NT) STAGE_B1((t + 2) % 3, (t + 2) * 32);
        __builtin_amdgcn_s_setprio(1);
#pragma unroll
        for (int mi = 0; mi < 2; ++mi)
#pragma unroll
            for (int ni = 0; ni < 4; ++ni)
                acc[mi + 2][ni] = mfma16(afr[mi], bfr[ni], acc[mi + 2][ni]);
        __builtin_amdgcn_s_setprio(0);
    }
#undef STAGE_A1
#undef STAGE_B1

#pragma unroll
    for (int ni = 0; ni < 4; ++ni) {
        const int colg = (int)col0 + wn * 64 + ni * 16 + (lane & 15);
        const float bcol = bias[colg];
#pragma unroll
        for (int mi = 0; mi < 4; ++mi) {
#pragma unroll
            for (int r = 0; r < 4; ++r) {
                const long rowg = row0 + wm * 64 + mi * 16 + (lane >> 4) * 4 + r;
                float vv = acc[mi][ni][r] + bcol;
                if (GELU) vv = 0.5f * vv * (1.0f + erff(vv * 0.70710678118f));
                C[rowg * ldc + colg] = f2b(vv);
            }
        }
    }
}

// ---------------- split-K 128x128 GEMM: 8 waves = 2 K-groups x 4 waves, depth-3 pipeline ----------------
template<bool OUTF32, bool GELU, bool RES, bool NTST>
__global__ __launch_bounds__(512, 2) void gemm4s(const ushort* __restrict__ A, int lda,
                                                 const ushort* __restrict__ Bt, int ldb,
                                                 const float* __restrict__ bias,
                                                 const float* __restrict__ res,
                                                 void* __restrict__ Cout,
                                                 int Nn, int K)
{
    extern __shared__ char smem[];   // A: g*32KB + buf*8KB (64KB) | B: 64KB @ +65536
    const int tid  = threadIdx.x;
    const int lane = tid & 63;
    const int g    = tid >> 8;              // K-group
    const int tg   = tid & 255;             // thread-in-group
    const int w4   = tg >> 6;               // wave-in-group 0..3
    const int wm   = w4 >> 1, wn = w4 & 1;
    const long row0 = (long)blockIdx.x * 128;
    const long col0 = (long)blockIdx.y * 128;
    const int mrow = lane & 15;
    const int xsl  = (((lane >> 4) ^ ((mrow >> 1) & 3))) * 8;  // swizzled read slot

    const int srow = tg >> 2;               // 0..63
    const int soff = (((tg & 3) ^ ((srow >> 1) & 3))) * 8;     // inverse-swizzled source slot
    const int kb   = g * (K >> 1);          // group K origin
    const ushort* Ag = A  + (row0 + srow) * (long)lda + kb + soff;
    const ushort* Bg = Bt + (col0 + srow) * (long)ldb + kb + soff;
    char* Als = smem + g * 32768;
    char* Bls = smem + 65536 + g * 32768;

#define STAGE4S(buf, k0)                                                          \
    do {                                                                          \
        gload_lds16(Ag + (k0),                  Als + ((buf) << 13) + w4 * 1024); \
        gload_lds16(Ag + 64 * (long)lda + (k0), Als + ((buf) << 13) + 4096 + w4 * 1024); \
        gload_lds16(Bg + (k0),                  Bls + ((buf) << 13) + w4 * 1024); \
        gload_lds16(Bg + 64 * (long)ldb + (k0), Bls + ((buf) << 13) + 4096 + w4 * 1024); \
    } while (0)

    const f32x4 zero = {0.f, 0.f, 0.f, 0.f};
    f32x4 acc[4][4];
#pragma unroll
    for (int m = 0; m < 4; ++m)
#pragma unroll
        for (int j = 0; j < 4; ++j) acc[m][j] = zero;

    const int NT2 = K >> 6;                 // tiles per group
    STAGE4S(0, 0);
    STAGE4S(1, 32);
    STAGE4S(2, 64);

    const int abase = (wm * 64 + mrow) * 32 + xsl;
    const int bbase = (wn * 64 + mrow) * 32 + xsl;

    for (int t = 0; t < NT2; ++t) {
        if      (t >= NT2 - 1) asm volatile("s_waitcnt vmcnt(0)" ::: "memory");
        else if (t == NT2 - 2) asm volatile("s_waitcnt vmcnt(4)" ::: "memory");
        else                   asm volatile("s_waitcnt vmcnt(8)" ::: "memory");
        __builtin_amdgcn_sched_barrier(0);
        __builtin_amdgcn_s_barrier();
        __builtin_amdgcn_sched_barrier(0);

        if (t + 3 < NT2) STAGE4S((t + 3) & 3, (t + 3) * 32);

        const ushort* Abase = (const ushort*)(Als + ((t & 3) << 13));
        const ushort* Bbase = (const ushort*)(Bls + ((t & 3) << 13));
        bf16x8 af[4], bfv[4];
#pragma unroll
        for (int m = 0; m < 4; ++m)
            af[m] = *(const bf16x8*)&Abase[abase + m * 512];
#pragma unroll
        for (int j = 0; j < 4; ++j)
            bfv[j] = *(const bf16x8*)&Bbase[bbase + j * 512];
        __builtin_amdgcn_s_setprio(1);
#pragma unroll
        for (int m = 0; m < 4; ++m)
#pragma unroll
            for (int j = 0; j < 4; ++j)
                acc[m][j] = mfma16(af[m], bfv[j], acc[m][j]);
        __builtin_amdgcn_s_setprio(0);
    }
#undef STAGE4S

    // ---- cross-group reduce: g1 -> LDS ([elem][thread] layout, conflict-free), g0 combines ----
    __syncthreads();
    float* xch = (float*)smem;              // 64KB exchange region
    if (g == 1) {
#pragma unroll
        for (int m = 0; m < 4; ++m)
#pragma unroll
            for (int j = 0; j < 4; ++j)
#pragma unroll
                for (int r = 0; r < 4; ++r)
                    xch[(m * 16 + j * 4 + r) * 256 + tg] = acc[m][j][r];
    }
    __syncthreads();
    if (g == 0) {
#pragma unroll
        for (int j = 0; j < 4; ++j) {
            const int colg  = (int)col0 + wn * 64 + j * 16 + mrow;
            const float bcol = bias[colg];
#pragma unroll
            for (int m = 0; m < 4; ++m) {
#pragma unroll
                for (int r = 0; r < 4; ++r) {
                    const long rowg = row0 + wm * 64 + m * 16 + (lane >> 4) * 4 + r;
                    float vv = acc[m][j][r] + xch[(m * 16 + j * 4 + r) * 256 + tg] + bcol;
                    if (RES)   vv += res[rowg * Nn + colg];
                    if (GELU)  vv = 0.5f * vv * (1.0f + erff(vv * 0.70710678118f));
                    if (OUTF32) {
                        if (NTST) __builtin_nontemporal_store(vv, (float*)Cout + rowg * Nn + colg);
                        else      ((float*)Cout)[rowg * Nn + colg] = vv;
                    } else {
                        ((ushort*)Cout)[rowg * Nn + colg] = f2b(vv);
                    }
                }
            }
        }
    }
}

// ---------------- V transpose: v (= qkv + 2048, stride QKVLD) -> vt[B,H,DHEAD,N] ----------------
__global__ __launch_bounds__(256) void transpose_v(const ushort* __restrict__ v,
                                                   ushort* __restrict__ vt)
{
    __shared__ ushort t[64][72];
    const int nb = blockIdx.x, bh = blockIdx.y, b = bh >> 4;
    const int hcol = (bh & 15) * DHEAD;
    const int tid  = threadIdx.x;
    const int rrow = tid >> 3;          // 0..31
    const int cch  = (tid & 7) * 8;
#pragma unroll
    for (int r = 0; r < 2; ++r) {
        const int nr = rrow + r * 32;
        *(uint4*)&t[nr][cch] =
            *(const uint4*)(v + ((long)(b * NSEQ + nb * 64 + nr)) * QKVLD + hcol + cch);
    }
    __syncthreads();
#pragma unroll
    for (int r = 0; r < 2; ++r) {
        const int d = rrow + r * 32;
        ushort tmp[8];
#pragma unroll
        for (int i = 0; i < 8; ++i) tmp[i] = t[cch + i][d];
        *(uint4*)(vt + ((long)bh * DHEAD + d) * NSEQ + nb * 64 + cch) = *(const uint4*)tmp;
    }
}

// ---------------- fused sigmoid attention: async gload_lds K/V double-buffer, 1 barrier/tile ----------------
// K/V tiles are [64][64] (unpadded, gload_lds-compatible) with slot swizzle s' = (s + row) & 7:
// inverse-permuted global source at stage time, swizzled slot at frag-read time (8 lanes/quad = floor).
// Counted vmcnt(4) leaves the 4 probs stores in flight; stage(t+1) issued after barrier(t) (reuse dist 2).
__global__ __launch_bounds__(256) void attn_kernel(const ushort* __restrict__ qkv,
                                                   const ushort* __restrict__ vt,
                                                   float* __restrict__ probs,
                                                   ushort* __restrict__ ao)
{
    __shared__ ushort KV[2][8192];      // per buf: K[64][64] @0, V[64][64] @4096 (elems)
    __shared__ __align__(16) float Pf[4][16][68];
    const int tid  = threadIdx.x;
    const int lane = tid & 63;
    const int w    = tid >> 6;
    const int qb   = blockIdx.x;
    const int bh   = blockIdx.y;
    const int b    = bh >> 4;
    const int q0   = qb * 64 + w * 16;
    const int mrow = lane & 15;
    const int q4   = lane >> 4;
    const int kof  = q4 * 8;            // for Q loads + Pf indexing
    const int hcol = (bh & 15) * DHEAD;
    const int NT   = NSEQ / 64;

    bf16x8 aq0, aq1;
    {
        const ushort* qp = qkv + ((long)(b * NSEQ + q0 + mrow)) * QKVLD + hcol;
        aq0 = *(const bf16x8*)(qp + kof);
        aq1 = *(const bf16x8*)(qp + 32 + kof);
    }

    const f32x4 zero = {0.f, 0.f, 0.f, 0.f};
    f32x4 acco[4];
#pragma unroll
    for (int dj = 0; dj < 4; ++dj) acco[dj] = zero;

    // staging: 256 threads x 2 chunks (rows srow, srow+32) per operand; dest linear chunk = tid*16B
    const int srow = tid >> 3;               // 0..31
    const int sp   = tid & 7;
    const int scol = ((sp - srow) & 7) * 8;  // inverse-swizzled source slot (32 ≡ 0 mod 8 -> same both sets)
    const ushort* km = qkv + 1024;
    const ushort* kg = km + (long)(b * NSEQ + srow) * QKVLD + hcol + scol;
    const ushort* vg = vt + ((long)bh * DHEAD + srow) * NSEQ + scol;
    char* kls = (char*)KV;

#define STAGE(buf, kt)                                                              \
    do {                                                                            \
        const long ko = (long)(kt) * 64 * QKVLD;                                    \
        const int  vo = (kt) * 64;                                                  \
        gload_lds16(kg + ko,                kls + (buf) * 16384 + w * 1024);        \
        gload_lds16(kg + ko + 32L * QKVLD,  kls + (buf) * 16384 + 4096 + w * 1024); \
        gload_lds16(vg + vo,                kls + (buf) * 16384 + 8192 + w * 1024); \
        gload_lds16(vg + vo + 32 * NSEQ,    kls + (buf) * 16384 + 12288 + w * 1024);\
    } while (0)

    STAGE(0, 0);

    for (int kt = 0; kt < NT; ++kt) {
        // drain this tile's 4 stage loads; keep the 4 newest vmem ops (probs stores) in flight
        if (kt == 0) asm volatile("s_waitcnt vmcnt(0)" ::: "memory");
        else         asm volatile("s_waitcnt vmcnt(4)" ::: "memory");
        __builtin_amdgcn_sched_barrier(0);
        __builtin_amdgcn_s_barrier();
        __builtin_amdgcn_sched_barrier(0);

        if (kt + 1 < NT) STAGE((kt + 1) & 1, kt + 1);
        __builtin_amdgcn_sched_barrier(0);   // pin: stores below must not hoist above stage loads

        const ushort* Kb = &KV[kt & 1][0];
        const ushort* Vb = &KV[kt & 1][4096];

        f32x4 s[4];
#pragma unroll
        for (int j = 0; j < 4; ++j) s[j] = zero;
#pragma unroll
        for (int j = 0; j < 4; ++j) {
            const int row = j * 16 + mrow;
            bf16x8 b0 = *(const bf16x8*)&Kb[row * 64 + ((q4 + mrow) & 7) * 8];
            bf16x8 b1 = *(const bf16x8*)&Kb[row * 64 + ((q4 + 4 + mrow) & 7) * 8];
            s[j] = mfma16(aq0, b0, s[j]);
            s[j] = mfma16(aq1, b1, s[j]);
        }

#pragma unroll
        for (int j = 0; j < 4; ++j) {
#pragma unroll
            for (int r = 0; r < 4; ++r) {
                const int rr = q4 * 4 + r;
                const float e  = __expf(-0.125f * s[j][r]);
                const float pv = __builtin_amdgcn_rcpf(1.0f + e);
                Pf[w][rr][j * 16 + mrow] = pv;
            }
        }

        // vectorized nontemporal probs store: 4x dwordx4 per lane (stay in flight across barrier)
        const long pbase = ((long)(bh * NSEQ + q0)) * NSEQ + kt * 64;
#pragma unroll
        for (int i = 0; i < 4; ++i) {
            const int rr = q4 + 4 * i;
            const f32x4 pv4 = *(const f32x4*)&Pf[w][rr][mrow * 4];
            __builtin_nontemporal_store(pv4, (f32x4*)(probs + pbase + (long)rr * NSEQ + mrow * 4));
        }

        // PV: rebuild bf16 A-frag from f32 LDS tile
#pragma unroll
        for (int ks = 0; ks < 2; ++ks) {
            const f32x4 f0 = *(const f32x4*)&Pf[w][mrow][ks * 32 + kof];
            const f32x4 f1 = *(const f32x4*)&Pf[w][mrow][ks * 32 + kof + 4];
            bf16x8 ap;
            ap[0] = (short)f2b(f0[0]); ap[1] = (short)f2b(f0[1]);
            ap[2] = (short)f2b(f0[2]); ap[3] = (short)f2b(f0[3]);
            ap[4] = (short)f2b(f1[0]); ap[5] = (short)f2b(f1[1]);
            ap[6] = (short)f2b(f1[2]); ap[7] = (short)f2b(f1[3]);
#pragma unroll
            for (int dj = 0; dj < 4; ++dj) {
                const int rowv = dj * 16 + mrow;
                bf16x8 bv = *(const bf16x8*)&Vb[rowv * 64 + ((q4 + 4 * ks + mrow) & 7) * 8];
                acco[dj] = mfma16(ap, bv, acco[dj]);
            }
        }
        // no second barrier: next tile writes the OTHER buffer; reuse protected by barrier(t+1)
    }
#undef STAGE

    const float sc = rsqrtf((float)NSEQ);
#pragma unroll
    for (int dj = 0; dj < 4; ++dj)
#pragma unroll
        for (int r = 0; r < 4; ++r) {
            const int rr = q4 * 4 + r;
            ao[((long)(b * NSEQ + q0 + rr)) * DMODEL + hcol + dj * 16 + mrow] =
                f2b(acco[dj][r] * sc);
        }
}

// ---------------- launch ----------------
extern "C" void kernel_launch(void* const* d_in, const int* in_sizes, int n_in,
                              void* d_out, int out_size, void* d_ws, size_t ws_size,
                              hipStream_t stream) {
    (void)in_sizes; (void)n_in; (void)out_size;
    const float* x    = (const float*)d_in[0];
    const float* wq   = (const float*)d_in[1];
    const float* bq   = (const float*)d_in[2];
    const float* wk   = (const float*)d_in[3];
    const float* bk   = (const float*)d_in[4];
    const float* wv   = (const float*)d_in[5];
    const float* bv   = (const float*)d_in[6];
    const float* wo   = (const float*)d_in[7];
    const float* bo   = (const float*)d_in[8];
    const float* ln1g = (const float*)d_in[9];
    const float* ln1b = (const float*)d_in[10];
    const float* ln2g = (const float*)d_in[11];
    const float* ln2b = (const float*)d_in[12];
    const float* w1   = (const float*)d_in[13];
    const float* b1   = (const float*)d_in[14];
    const float* w2   = (const float*)d_in[15];
    const float* b2   = (const float*)d_in[16];

    char* ws = (char*)d_ws;
    const size_t MB = 1u << 20;
    ushort* wqkv_t  = (ushort*)(ws + 0 * MB);    // [3072][1024] bf16, 6MB
    ushort* wo_t    = (ushort*)(ws + 6 * MB);    // [1024][1024], 2MB
    ushort* w1_t    = (ushort*)(ws + 8 * MB);    // [4096][1024], 8MB
    ushort* w2_t    = (ushort*)(ws + 16 * MB);   // [1024][4096], 8MB
    float*  bqkv    = (float*) (ws + 24 * MB);   // 3072 + 1024 zeros
    ushort* normed  = (ushort*)(ws + 25 * MB);   // [4096][1024], 8MB
    ushort* qkvbuf  = (ushort*)(ws + 33 * MB);   // [4096][3072], 24MB
    ushort* vtb     = (ushort*)(ws + 57 * MB);   // [32][64][2048], 8MB
    ushort* attn_o  = (ushort*)(ws + 65 * MB);   // [4096][1024], 8MB
    float*  x1      = (float*) (ws + 41 * MB);   // 16MB, aliases qkvbuf tail (dead after attn)
    ushort* normed2 = (ushort*)(ws + 25 * MB);   // aliases normed (dead)
    ushort* hbuf    = (ushort*)(ws + 57 * MB);   // halves: [4096][2048] 16MB; full: [4096][4096] 32MB
    const float* bzero = bqkv + 3072;
    const bool fullff = (ws_size >= 89 * MB);

    float* xout  = (float*)d_out;
    float* probs = xout + (size_t)MROWS * DMODEL;

    // fused prep: all weight casts (LDS transpose) + bias concat + LN1 (one launch)
    prep<<<7184, 256, 0, stream>>>(wq, wk, wv, wo, w1, w2, bq, bk, bv,
                                   x, ln1g, ln1b,
                                   wqkv_t, wo_t, w1_t, w2_t, bqkv, normed);

    // fused QKV projection: [4096,1024] @ [1024,3072] -> qkvbuf (128x256 tiles, 384 blocks)
    gemm128<false><<<dim3(32, 12), 512, 72 * 1024, stream>>>(
        normed, DMODEL, wqkv_t, DMODEL, bqkv, qkvbuf, QKVLD, DMODEL);

    // V -> V^T per head
    transpose_v<<<dim3(NSEQ / 64, NBATCH * NHEADS), 256, 0, stream>>>(qkvbuf + 2048, vtb);

    // fused sigmoid attention (writes probs + attn_out/sqrt(N)), async dbuf, 1 barrier/tile
    attn_kernel<<<dim3(NSEQ / 64, NBATCH * NHEADS), 256, 0, stream>>>(
        qkvbuf, vtb, probs, attn_o);

    // out projection + residual -> x1 (f32), split-K deep pipeline
    gemm4s<true, false, true, false><<<dim3(32, 8), 512, 128 * 1024, stream>>>(
        attn_o, DMODEL, wo_t, DMODEL, bo, x, x1, DMODEL, DMODEL);

    // LN2
    ln_kernel<<<MROWS, 256, 0, stream>>>(x1, ln2g, ln2b, normed2);

    if (fullff) {
        // FF1 full-width -> hbuf [4096][4096] (128x256 tiles, 512 blocks)
        gemm128<true><<<dim3(32, 16), 512, 72 * 1024, stream>>>(
            normed2, DMODEL, w1_t, DMODEL, b1, hbuf, DFF, DMODEL);
        // FF2 single launch, K=4096, + residual -> out (f32, nontemporal)
        gemm4s<true, false, true, true><<<dim3(32, 8), 512, 128 * 1024, stream>>>(
            hbuf, DFF, w2_t, DFF, b2, x1, xout, DMODEL, DFF);
    } else {
        // FF halves (hbuf = 16MB)
        gemm128<true><<<dim3(32, 8), 512, 72 * 1024, stream>>>(
            normed2, DMODEL, w1_t, DMODEL, b1, hbuf, 2048, DMODEL);
        gemm4s<true, false, true, false><<<dim3(32, 8), 512, 128 * 1024, stream>>>(
            hbuf, 2048, w2_t, DFF, b2, x1, xout, DMODEL, 2048);
        gemm128<true><<<dim3(32, 8), 512, 72 * 1024, stream>>>(
            normed2, DMODEL, w1_t + 2048 * 1024, DMODEL, b1 + 2048, hbuf, 2048, DMODEL);
        gemm4s<true, false, true, true><<<dim3(32, 8), 512, 128 * 1024, stream>>>(
            hbuf, 2048, w2_t + 2048, DFF, bzero, xout, xout, DMODEL, 2048);
    }
}

// Round 15
// 314.711 us; speedup vs baseline: 1.0571x; 1.0571x over previous
//
#include <hip/hip_runtime.h>
#include <hip/hip_bf16.h>
#include <math.h>

#define DMODEL 1024
#define NSEQ   2048
#define NBATCH 2
#define NHEADS 16
#define DHEAD  64
#define DFF    4096
#define MROWS  (NBATCH*NSEQ)
#define QKVLD  3072   // fused qkv row stride

typedef __attribute__((ext_vector_type(8))) short bf16x8;
typedef __attribute__((ext_vector_type(4))) float f32x4;

static __device__ __forceinline__ ushort f2b(float f) {
    return __builtin_bit_cast(ushort, (__bf16)f);
}

static __device__ __forceinline__ f32x4 mfma16(bf16x8 a, bf16x8 b, f32x4 c) {
    return __builtin_amdgcn_mfma_f32_16x16x32_bf16(a, b, c, 0, 0, 0);
}

static __device__ __forceinline__ void gload_lds16(const void* g, void* lds) {
    __builtin_amdgcn_global_load_lds((const __attribute__((address_space(1))) void*)g,
                                     (__attribute__((address_space(3))) void*)lds,
                                     16, 0, 0);
}

// LDS-only barrier: does NOT drain vmcnt (global stores stay in flight).
static __device__ __forceinline__ void softbar() {
    __builtin_amdgcn_sched_barrier(0);
    asm volatile("s_waitcnt lgkmcnt(0)" ::: "memory");
    __builtin_amdgcn_s_barrier();
    __builtin_amdgcn_sched_barrier(0);
}

// ---------------- fused prep: 6 weight cast+transposes (LDS transpose) + bias concat + LN1 ----------------
static __device__ __forceinline__ void cast_tile_lds(const float* __restrict__ W,
                                                     ushort* __restrict__ Wt,
                                                     int K, int Nn, int bx, int by, int t,
                                                     float (*lds)[65])
{
    const int n0 = bx * 64;
    const int k0 = by * 64;
#pragma unroll
    for (int r = 0; r < 4; ++r) {
        const int kr = (t >> 4) + r * 16;
        const int nc = (t & 15) * 4;
        const float4 v = *(const float4*)(W + (long)(k0 + kr) * Nn + n0 + nc);
        lds[kr][nc] = v.x; lds[kr][nc + 1] = v.y; lds[kr][nc + 2] = v.z; lds[kr][nc + 3] = v.w;
    }
    __syncthreads();
    const int n  = t >> 2;            // 0..63 output row
    const int kc = (t & 3) * 16;      // 16 k per lane; 4 lanes cover 128B contiguous
    ushort tmp[16];
#pragma unroll
    for (int i = 0; i < 16; ++i) tmp[i] = f2b(lds[kc + i][n]);
    *(uint4*)(Wt + (long)(n0 + n) * K + k0 + kc)     = *(const uint4*)tmp;
    *(uint4*)(Wt + (long)(n0 + n) * K + k0 + kc + 8) = *(const uint4*)(tmp + 8);
}

__global__ __launch_bounds__(256) void prep(const float* __restrict__ wq,
                                            const float* __restrict__ wk,
                                            const float* __restrict__ wv,
                                            const float* __restrict__ wo,
                                            const float* __restrict__ w1,
                                            const float* __restrict__ w2,
                                            const float* __restrict__ bq,
                                            const float* __restrict__ bk,
                                            const float* __restrict__ bv,
                                            const float* __restrict__ x,
                                            const float* __restrict__ ln1g,
                                            const float* __restrict__ ln1b,
                                            ushort* __restrict__ wqkv_t,
                                            ushort* __restrict__ wo_t,
                                            ushort* __restrict__ w1_t,
                                            ushort* __restrict__ w2_t,
                                            float* __restrict__ bqkv,
                                            ushort* __restrict__ normed)
{
    __shared__ float red[4];
    __shared__ float tl[64][65];
    const int id  = blockIdx.x;
    const int tid = threadIdx.x;

    if (id < 256) {                       // wq: 16x16 tiles
        cast_tile_lds(wq, wqkv_t, 1024, 1024, id & 15, id >> 4, tid, tl);
    } else if (id < 512) {
        const int i2 = id - 256;
        cast_tile_lds(wk, wqkv_t + 1024 * 1024, 1024, 1024, i2 & 15, i2 >> 4, tid, tl);
    } else if (id < 768) {
        const int i2 = id - 512;
        cast_tile_lds(wv, wqkv_t + 2048 * 1024, 1024, 1024, i2 & 15, i2 >> 4, tid, tl);
    } else if (id < 1024) {
        const int i2 = id - 768;
        cast_tile_lds(wo, wo_t, 1024, 1024, i2 & 15, i2 >> 4, tid, tl);
    } else if (id < 2048) {               // w1: [1024][4096] -> Wt[4096][1024]
        const int i2 = id - 1024;
        cast_tile_lds(w1, w1_t, 1024, 4096, i2 & 63, i2 >> 6, tid, tl);
    } else if (id < 3072) {               // w2: [4096][1024] -> Wt[1024][4096]
        const int i2 = id - 2048;
        cast_tile_lds(w2, w2_t, 4096, 1024, i2 & 15, i2 >> 4, tid, tl);
    } else if (id < 3088) {
        const int t = (id - 3072) * 256 + tid;
        float v = 0.0f;
        if (t < 1024)      v = bq[t];
        else if (t < 2048) v = bk[t - 1024];
        else if (t < 3072) v = bv[t - 2048];
        bqkv[t] = v;
    } else {
        const int row = id - 3088;
        const float4 v = ((const float4*)(x + (long)row * DMODEL))[tid];
        float s = v.x + v.y + v.z + v.w;
#pragma unroll
        for (int o = 32; o; o >>= 1) s += __shfl_down(s, o, 64);
        if ((tid & 63) == 0) red[tid >> 6] = s;
        __syncthreads();
        const float mu = (red[0] + red[1] + red[2] + red[3]) * (1.0f / DMODEL);
        __syncthreads();
        const float d0 = v.x - mu, d1 = v.y - mu, d2 = v.z - mu, d3 = v.w - mu;
        float s2 = d0*d0 + d1*d1 + d2*d2 + d3*d3;
#pragma unroll
        for (int o = 32; o; o >>= 1) s2 += __shfl_down(s2, o, 64);
        if ((tid & 63) == 0) red[tid >> 6] = s2;
        __syncthreads();
        const float inv = rsqrtf((red[0] + red[1] + red[2] + red[3]) * (1.0f / DMODEL) + 1e-5f);
        const float4 gg = ((const float4*)ln1g)[tid];
        const float4 bv4 = ((const float4*)ln1b)[tid];
        ushort4 o4;
        o4.x = f2b(d0 * inv * gg.x + bv4.x);
        o4.y = f2b(d1 * inv * gg.y + bv4.y);
        o4.z = f2b(d2 * inv * gg.z + bv4.z);
        o4.w = f2b(d3 * inv * gg.w + bv4.w);
        ((ushort4*)(normed + (long)row * DMODEL))[tid] = o4;
    }
}

// ---------------- LayerNorm (standalone, used for LN2) ----------------
__global__ __launch_bounds__(256) void ln_kernel(const float* __restrict__ x,
                                                 const float* __restrict__ g,
                                                 const float* __restrict__ bb,
                                                 ushort* __restrict__ out)
{
    const int row = blockIdx.x;
    const int tid = threadIdx.x;
    const float4 v = ((const float4*)(x + (long)row * DMODEL))[tid];
    float s = v.x + v.y + v.z + v.w;
#pragma unroll
    for (int o = 32; o; o >>= 1) s += __shfl_down(s, o, 64);
    __shared__ float red[4];
    if ((tid & 63) == 0) red[tid >> 6] = s;
    __syncthreads();
    const float mu = (red[0] + red[1] + red[2] + red[3]) * (1.0f / DMODEL);
    __syncthreads();
    const float d0 = v.x - mu, d1 = v.y - mu, d2 = v.z - mu, d3 = v.w - mu;
    float s2 = d0*d0 + d1*d1 + d2*d2 + d3*d3;
#pragma unroll
    for (int o = 32; o; o >>= 1) s2 += __shfl_down(s2, o, 64);
    if ((tid & 63) == 0) red[tid >> 6] = s2;
    __syncthreads();
    const float inv = rsqrtf((red[0] + red[1] + red[2] + red[3]) * (1.0f / DMODEL) + 1e-5f);
    const float4 gg = ((const float4*)g)[tid];
    const float4 bv = ((const float4*)bb)[tid];
    ushort4 o4;
    o4.x = f2b(d0 * inv * gg.x + bv.x);
    o4.y = f2b(d1 * inv * gg.y + bv.y);
    o4.z = f2b(d2 * inv * gg.z + bv.z);
    o4.w = f2b(d3 * inv * gg.w + bv.w);
    ((ushort4*)(out + (long)row * DMODEL))[tid] = o4;
}

// ---------------- deep-pipelined 128x256 GEMM, 8 waves, BK=32, 3 LDS buffers, depth-2 ----------------
template<bool GELU>
__global__ __launch_bounds__(512, 2) void gemm128(const ushort* __restrict__ A, int lda,
                                                  const ushort* __restrict__ Bt, int ldb,
                                                  const float* __restrict__ bias,
                                                  ushort* __restrict__ C, int ldc, int K)
{
    extern __shared__ char smem[];
    const int tid  = threadIdx.x;
    const int lane = tid & 63;
    const int w    = tid >> 6;
    const int wm   = w >> 2;                // 0..1  (M half, 64 rows each)
    const int wn   = w & 3;                 // 0..3  (N quarter)
    const long row0 = (long)blockIdx.x * 128;
    const long col0 = (long)blockIdx.y * 256;

    const int srow = tid >> 2;              // 0..127
    const int scol = (((tid & 3) ^ ((srow >> 1) & 3))) * 8;   // inverse-swizzled source slot
    const ushort* Ag = A  + (row0 + srow) * (long)lda + scol;
    const ushort* Bg = Bt + (col0 + srow) * (long)ldb + scol;

#define STAGE_A1(buf, k0)                                                                  \
    gload_lds16(Ag + (k0), smem + (buf) * 8192 + w * 1024)
#define STAGE_B1(buf, k0)                                                                  \
    do {                                                                                   \
        gload_lds16(Bg + (k0),                   smem + 24576 + (buf) * 16384 + w * 1024); \
        gload_lds16(Bg + 128 * (long)ldb + (k0), smem + 24576 + (buf) * 16384 + 8192 + w * 1024); \
    } while (0)

    const f32x4 zero = {0.f, 0.f, 0.f, 0.f};
    f32x4 acc[4][4];
#pragma unroll
    for (int m = 0; m < 4; ++m)
#pragma unroll
        for (int j = 0; j < 4; ++j) acc[m][j] = zero;

    const int NT = K >> 5;
    STAGE_A1(0, 0);  STAGE_B1(0, 0);
    STAGE_A1(1, 32); STAGE_B1(1, 32);

    const int mrow = lane & 15;
    const int xsl  = (((lane >> 4) ^ ((mrow >> 1) & 3))) * 8;  // swizzled read slot
    const int abase = (wm * 64 + mrow) * 32 + xsl;
    const int bbase = (wn * 64 + mrow) * 32 + xsl;

    for (int t = 0; t < NT; ++t) {
        if (t == NT - 1) asm volatile("s_waitcnt vmcnt(0)" ::: "memory");
        else             asm volatile("s_waitcnt vmcnt(3)" ::: "memory");
        __builtin_amdgcn_sched_barrier(0);
        __builtin_amdgcn_s_barrier();
        __builtin_amdgcn_sched_barrier(0);

        const int cb = t % 3;
        const ushort* Abase = (const ushort*)(smem + cb * 8192);
        const ushort* Bbase = (const ushort*)(smem + 24576 + cb * 16384);

        bf16x8 bfr[4], afr[2];
#pragma unroll
        for (int ni = 0; ni < 4; ++ni)
            bfr[ni] = *(const bf16x8*)&Bbase[bbase + ni * 512];
#pragma unroll
        for (int mi = 0; mi < 2; ++mi)
            afr[mi] = *(const bf16x8*)&Abase[abase + mi * 512];
        if (t + 2 < NT) STAGE_A1((t + 2) % 3, (t + 2) * 32);
        __builtin_amdgcn_s_setprio(1);
#pragma unroll
        for (int mi = 0; mi < 2; ++mi)
#pragma unroll
            for (int ni = 0; ni < 4; ++ni)
                acc[mi][ni] = mfma16(afr[mi], bfr[ni], acc[mi][ni]);
        __builtin_amdgcn_s_setprio(0);

#pragma unroll
        for (int mi = 0; mi < 2; ++mi)
            afr[mi] = *(const bf16x8*)&Abase[abase + (mi + 2) * 512];
        if (t + 2 < NT) STAGE_B1((t + 2) % 3, (t + 2) * 32);
        __builtin_amdgcn_s_setprio(1);
#pragma unroll
        for (int mi = 0; mi < 2; ++mi)
#pragma unroll
            for (int ni = 0; ni < 4; ++ni)
                acc[mi + 2][ni] = mfma16(afr[mi], bfr[ni], acc[mi + 2][ni]);
        __builtin_amdgcn_s_setprio(0);
    }
#undef STAGE_A1
#undef STAGE_B1

#pragma unroll
    for (int ni = 0; ni < 4; ++ni) {
        const int colg = (int)col0 + wn * 64 + ni * 16 + (lane & 15);
        const float bcol = bias[colg];
#pragma unroll
        for (int mi = 0; mi < 4; ++mi) {
#pragma unroll
            for (int r = 0; r < 4; ++r) {
                const long rowg = row0 + wm * 64 + mi * 16 + (lane >> 4) * 4 + r;
                float vv = acc[mi][ni][r] + bcol;
                if (GELU) vv = 0.5f * vv * (1.0f + erff(vv * 0.70710678118f));
                C[rowg * ldc + colg] = f2b(vv);
            }
        }
    }
}

// ---------------- split-K 128x128 GEMM: 8 waves = 2 K-groups x 4 waves, depth-3 pipeline ----------------
template<bool OUTF32, bool GELU, bool RES, bool NTST>
__global__ __launch_bounds__(512, 2) void gemm4s(const ushort* __restrict__ A, int lda,
                                                 const ushort* __restrict__ Bt, int ldb,
                                                 const float* __restrict__ bias,
                                                 const float* __restrict__ res,
                                                 void* __restrict__ Cout,
                                                 int Nn, int K)
{
    extern __shared__ char smem[];   // A: g*32KB + buf*8KB (64KB) | B: 64KB @ +65536
    const int tid  = threadIdx.x;
    const int lane = tid & 63;
    const int g    = tid >> 8;              // K-group
    const int tg   = tid & 255;             // thread-in-group
    const int w4   = tg >> 6;               // wave-in-group 0..3
    const int wm   = w4 >> 1, wn = w4 & 1;
    const long row0 = (long)blockIdx.x * 128;
    const long col0 = (long)blockIdx.y * 128;
    const int mrow = lane & 15;
    const int xsl  = (((lane >> 4) ^ ((mrow >> 1) & 3))) * 8;  // swizzled read slot

    const int srow = tg >> 2;               // 0..63
    const int soff = (((tg & 3) ^ ((srow >> 1) & 3))) * 8;     // inverse-swizzled source slot
    const int kb   = g * (K >> 1);          // group K origin
    const ushort* Ag = A  + (row0 + srow) * (long)lda + kb + soff;
    const ushort* Bg = Bt + (col0 + srow) * (long)ldb + kb + soff;
    char* Als = smem + g * 32768;
    char* Bls = smem + 65536 + g * 32768;

#define STAGE4S(buf, k0)                                                          \
    do {                                                                          \
        gload_lds16(Ag + (k0),                  Als + ((buf) << 13) + w4 * 1024); \
        gload_lds16(Ag + 64 * (long)lda + (k0), Als + ((buf) << 13) + 4096 + w4 * 1024); \
        gload_lds16(Bg + (k0),                  Bls + ((buf) << 13) + w4 * 1024); \
        gload_lds16(Bg + 64 * (long)ldb + (k0), Bls + ((buf) << 13) + 4096 + w4 * 1024); \
    } while (0)

    const f32x4 zero = {0.f, 0.f, 0.f, 0.f};
    f32x4 acc[4][4];
#pragma unroll
    for (int m = 0; m < 4; ++m)
#pragma unroll
        for (int j = 0; j < 4; ++j) acc[m][j] = zero;

    const int NT2 = K >> 6;                 // tiles per group
    STAGE4S(0, 0);
    STAGE4S(1, 32);
    STAGE4S(2, 64);

    const int abase = (wm * 64 + mrow) * 32 + xsl;
    const int bbase = (wn * 64 + mrow) * 32 + xsl;

    for (int t = 0; t < NT2; ++t) {
        if      (t >= NT2 - 1) asm volatile("s_waitcnt vmcnt(0)" ::: "memory");
        else if (t == NT2 - 2) asm volatile("s_waitcnt vmcnt(4)" ::: "memory");
        else                   asm volatile("s_waitcnt vmcnt(8)" ::: "memory");
        __builtin_amdgcn_sched_barrier(0);
        __builtin_amdgcn_s_barrier();
        __builtin_amdgcn_sched_barrier(0);

        if (t + 3 < NT2) STAGE4S((t + 3) & 3, (t + 3) * 32);

        const ushort* Abase = (const ushort*)(Als + ((t & 3) << 13));
        const ushort* Bbase = (const ushort*)(Bls + ((t & 3) << 13));
        bf16x8 af[4], bfv[4];
#pragma unroll
        for (int m = 0; m < 4; ++m)
            af[m] = *(const bf16x8*)&Abase[abase + m * 512];
#pragma unroll
        for (int j = 0; j < 4; ++j)
            bfv[j] = *(const bf16x8*)&Bbase[bbase + j * 512];
        __builtin_amdgcn_s_setprio(1);
#pragma unroll
        for (int m = 0; m < 4; ++m)
#pragma unroll
            for (int j = 0; j < 4; ++j)
                acc[m][j] = mfma16(af[m], bfv[j], acc[m][j]);
        __builtin_amdgcn_s_setprio(0);
    }
#undef STAGE4S

    // ---- cross-group reduce: g1 -> LDS ([elem][thread] layout, conflict-free), g0 combines ----
    __syncthreads();
    float* xch = (float*)smem;              // 64KB exchange region
    if (g == 1) {
#pragma unroll
        for (int m = 0; m < 4; ++m)
#pragma unroll
            for (int j = 0; j < 4; ++j)
#pragma unroll
                for (int r = 0; r < 4; ++r)
                    xch[(m * 16 + j * 4 + r) * 256 + tg] = acc[m][j][r];
    }
    __syncthreads();
    if (g == 0) {
#pragma unroll
        for (int j = 0; j < 4; ++j) {
            const int colg  = (int)col0 + wn * 64 + j * 16 + mrow;
            const float bcol = bias[colg];
#pragma unroll
            for (int m = 0; m < 4; ++m) {
#pragma unroll
                for (int r = 0; r < 4; ++r) {
                    const long rowg = row0 + wm * 64 + m * 16 + (lane >> 4) * 4 + r;
                    float vv = acc[m][j][r] + xch[(m * 16 + j * 4 + r) * 256 + tg] + bcol;
                    if (RES)   vv += res[rowg * Nn + colg];
                    if (GELU)  vv = 0.5f * vv * (1.0f + erff(vv * 0.70710678118f));
                    if (OUTF32) {
                        if (NTST) __builtin_nontemporal_store(vv, (float*)Cout + rowg * Nn + colg);
                        else      ((float*)Cout)[rowg * Nn + colg] = vv;
                    } else {
                        ((ushort*)Cout)[rowg * Nn + colg] = f2b(vv);
                    }
                }
            }
        }
    }
}

// ---------------- V transpose: v (= qkv + 2048, stride QKVLD) -> vt[B,H,DHEAD,N] ----------------
__global__ __launch_bounds__(256) void transpose_v(const ushort* __restrict__ v,
                                                   ushort* __restrict__ vt)
{
    __shared__ ushort t[64][72];
    const int nb = blockIdx.x, bh = blockIdx.y, b = bh >> 4;
    const int hcol = (bh & 15) * DHEAD;
    const int tid  = threadIdx.x;
    const int rrow = tid >> 3;          // 0..31
    const int cch  = (tid & 7) * 8;
#pragma unroll
    for (int r = 0; r < 2; ++r) {
        const int nr = rrow + r * 32;
        *(uint4*)&t[nr][cch] =
            *(const uint4*)(v + ((long)(b * NSEQ + nb * 64 + nr)) * QKVLD + hcol + cch);
    }
    __syncthreads();
#pragma unroll
    for (int r = 0; r < 2; ++r) {
        const int d = rrow + r * 32;
        ushort tmp[8];
#pragma unroll
        for (int i = 0; i < 8; ++i) tmp[i] = t[cch + i][d];
        *(uint4*)(vt + ((long)bh * DHEAD + d) * NSEQ + nb * 64 + cch) = *(const uint4*)tmp;
    }
}

// ---------------- fused sigmoid attention (QBLK=64, LDS-staged, softbar, XCD-swizzled) ----------------
// XCD remap: the 32 q-blocks of each (b,h) land on ONE XCD so its K/V panels live in a single
// L2 (no cross-XCD replication). Bijective: lin=x+32y; xcd=lin&7; idx=lin>>3; bh=xcd*4+(idx>>5); qb=idx&31.
__global__ __launch_bounds__(256) void attn_kernel(const ushort* __restrict__ qkv,
                                                   const ushort* __restrict__ vt,
                                                   float* __restrict__ probs,
                                                   ushort* __restrict__ ao)
{
    __shared__ ushort Ks[64][72];
    __shared__ ushort Vs[64][72];
    __shared__ __align__(16) float Pf[4][16][68];
    const int tid  = threadIdx.x;
    const int lane = tid & 63;
    const int w    = tid >> 6;
    const int lin  = blockIdx.x + 32 * blockIdx.y;
    const int xcd  = lin & 7;
    const int idx  = lin >> 3;
    const int bh   = xcd * 4 + (idx >> 5);
    const int qb   = idx & 31;
    const int b    = bh >> 4;
    const int q0   = qb * 64 + w * 16;
    const int mrow = lane & 15;
    const int kof  = (lane >> 4) * 8;
    const int hcol = (bh & 15) * DHEAD;
    const int NT   = NSEQ / 64;

    bf16x8 aq0, aq1;
    {
        const ushort* qp = qkv + ((long)(b * NSEQ + q0 + mrow)) * QKVLD + hcol;
        aq0 = *(const bf16x8*)(qp + kof);
        aq1 = *(const bf16x8*)(qp + 32 + kof);
    }

    const f32x4 zero = {0.f, 0.f, 0.f, 0.f};
    f32x4 acco[4];
#pragma unroll
    for (int dj = 0; dj < 4; ++dj) acco[dj] = zero;

    const int srow = tid >> 3;          // 0..31
    const int sch  = (tid & 7) * 8;
    const ushort* km = qkv + 1024;

    uint4 kr0, kr1, vr0, vr1;
#define LOADT(kt)                                                                          \
    do {                                                                                   \
        kr0 = *(const uint4*)(km + ((long)(b * NSEQ + (kt) * 64 + srow)) * QKVLD + hcol + sch);       \
        kr1 = *(const uint4*)(km + ((long)(b * NSEQ + (kt) * 64 + srow + 32)) * QKVLD + hcol + sch);  \
        vr0 = *(const uint4*)(vt + ((long)bh * DHEAD + srow) * NSEQ + (kt) * 64 + sch);               \
        vr1 = *(const uint4*)(vt + ((long)bh * DHEAD + srow + 32) * NSEQ + (kt) * 64 + sch);          \
    } while (0)

    LOADT(0);

    for (int kt = 0; kt < NT; ++kt) {
        *(uint4*)&Ks[srow][sch]      = kr0;
        *(uint4*)&Ks[srow + 32][sch] = kr1;
        *(uint4*)&Vs[srow][sch]      = vr0;
        *(uint4*)&Vs[srow + 32][sch] = vr1;
        softbar();                         // LDS visible; stores NOT drained
        if (kt + 1 < NT) LOADT(kt + 1);    // issued before this tile's probs stores

        f32x4 s[4];
#pragma unroll
        for (int j = 0; j < 4; ++j) s[j] = zero;
#pragma unroll
        for (int j = 0; j < 4; ++j) {
            bf16x8 b0 = *(const bf16x8*)&Ks[j * 16 + mrow][kof];
            bf16x8 b1 = *(const bf16x8*)&Ks[j * 16 + mrow][32 + kof];
            s[j] = mfma16(aq0, b0, s[j]);
            s[j] = mfma16(aq1, b1, s[j]);
        }

#pragma unroll
        for (int j = 0; j < 4; ++j) {
#pragma unroll
            for (int r = 0; r < 4; ++r) {
                const int rr = (lane >> 4) * 4 + r;
                const float e  = __expf(-0.125f * s[j][r]);
                const float pv = __builtin_amdgcn_rcpf(1.0f + e);
                Pf[w][rr][j * 16 + mrow] = pv;
            }
        }

        // vectorized nontemporal probs store: 4x dwordx4 per lane
        const long pbase = ((long)(bh * NSEQ + q0)) * NSEQ + kt * 64;
#pragma unroll
        for (int i = 0; i < 4; ++i) {
            const int rr = (lane >> 4) + 4 * i;
            const f32x4 pv4 = *(const f32x4*)&Pf[w][rr][mrow * 4];
            __builtin_nontemporal_store(pv4, (f32x4*)(probs + pbase + (long)rr * NSEQ + mrow * 4));
        }

        // PV: rebuild bf16 A-frag from f32 LDS tile
#pragma unroll
        for (int ks = 0; ks < 2; ++ks) {
            const f32x4 f0 = *(const f32x4*)&Pf[w][mrow][ks * 32 + kof];
            const f32x4 f1 = *(const f32x4*)&Pf[w][mrow][ks * 32 + kof + 4];
            bf16x8 ap;
            ap[0] = (short)f2b(f0[0]); ap[1] = (short)f2b(f0[1]);
            ap[2] = (short)f2b(f0[2]); ap[3] = (short)f2b(f0[3]);
            ap[4] = (short)f2b(f1[0]); ap[5] = (short)f2b(f1[1]);
            ap[6] = (short)f2b(f1[2]); ap[7] = (short)f2b(f1[3]);
#pragma unroll
            for (int dj = 0; dj < 4; ++dj) {
                bf16x8 bv = *(const bf16x8*)&Vs[dj * 16 + mrow][ks * 32 + kof];
                acco[dj] = mfma16(ap, bv, acco[dj]);
            }
        }
        softbar();                         // reads done; next tile may overwrite LDS
    }
#undef LOADT

    const float sc = rsqrtf((float)NSEQ);
#pragma unroll
    for (int dj = 0; dj < 4; ++dj)
#pragma unroll
        for (int r = 0; r < 4; ++r) {
            const int rr = (lane >> 4) * 4 + r;
            ao[((long)(b * NSEQ + q0 + rr)) * DMODEL + hcol + dj * 16 + mrow] =
                f2b(acco[dj][r] * sc);
        }
}

// ---------------- launch ----------------
extern "C" void kernel_launch(void* const* d_in, const int* in_sizes, int n_in,
                              void* d_out, int out_size, void* d_ws, size_t ws_size,
                              hipStream_t stream) {
    (void)in_sizes; (void)n_in; (void)out_size;
    const float* x    = (const float*)d_in[0];
    const float* wq   = (const float*)d_in[1];
    const float* bq   = (const float*)d_in[2];
    const float* wk   = (const float*)d_in[3];
    const float* bk   = (const float*)d_in[4];
    const float* wv   = (const float*)d_in[5];
    const float* bv   = (const float*)d_in[6];
    const float* wo   = (const float*)d_in[7];
    const float* bo   = (const float*)d_in[8];
    const float* ln1g = (const float*)d_in[9];
    const float* ln1b = (const float*)d_in[10];
    const float* ln2g = (const float*)d_in[11];
    const float* ln2b = (const float*)d_in[12];
    const float* w1   = (const float*)d_in[13];
    const float* b1   = (const float*)d_in[14];
    const float* w2   = (const float*)d_in[15];
    const float* b2   = (const float*)d_in[16];

    char* ws = (char*)d_ws;
    const size_t MB = 1u << 20;
    ushort* wqkv_t  = (ushort*)(ws + 0 * MB);    // [3072][1024] bf16, 6MB
    ushort* wo_t    = (ushort*)(ws + 6 * MB);    // [1024][1024], 2MB
    ushort* w1_t    = (ushort*)(ws + 8 * MB);    // [4096][1024], 8MB
    ushort* w2_t    = (ushort*)(ws + 16 * MB);   // [1024][4096], 8MB
    float*  bqkv    = (float*) (ws + 24 * MB);   // 3072 + 1024 zeros
    ushort* normed  = (ushort*)(ws + 25 * MB);   // [4096][1024], 8MB
    ushort* qkvbuf  = (ushort*)(ws + 33 * MB);   // [4096][3072], 24MB
    ushort* vtb     = (ushort*)(ws + 57 * MB);   // [32][64][2048], 8MB
    ushort* attn_o  = (ushort*)(ws + 65 * MB);   // [4096][1024], 8MB
    float*  x1      = (float*) (ws + 41 * MB);   // 16MB, aliases qkvbuf tail (dead after attn)
    ushort* normed2 = (ushort*)(ws + 25 * MB);   // aliases normed (dead)
    ushort* hbuf    = (ushort*)(ws + 57 * MB);   // halves: [4096][2048] 16MB; full: [4096][4096] 32MB
    const float* bzero = bqkv + 3072;
    const bool fullff = (ws_size >= 89 * MB);

    float* xout  = (float*)d_out;
    float* probs = xout + (size_t)MROWS * DMODEL;

    // fused prep: all weight casts (LDS transpose) + bias concat + LN1 (one launch)
    prep<<<7184, 256, 0, stream>>>(wq, wk, wv, wo, w1, w2, bq, bk, bv,
                                   x, ln1g, ln1b,
                                   wqkv_t, wo_t, w1_t, w2_t, bqkv, normed);

    // fused QKV projection: [4096,1024] @ [1024,3072] -> qkvbuf (128x256 tiles, 384 blocks)
    gemm128<false><<<dim3(32, 12), 512, 72 * 1024, stream>>>(
        normed, DMODEL, wqkv_t, DMODEL, bqkv, qkvbuf, QKVLD, DMODEL);

    // V -> V^T per head
    transpose_v<<<dim3(NSEQ / 64, NBATCH * NHEADS), 256, 0, stream>>>(qkvbuf + 2048, vtb);

    // fused sigmoid attention (writes probs + attn_out/sqrt(N)), XCD-swizzled
    attn_kernel<<<dim3(NSEQ / 64, NBATCH * NHEADS), 256, 0, stream>>>(
        qkvbuf, vtb, probs, attn_o);

    // out projection + residual -> x1 (f32), split-K deep pipeline
    gemm4s<true, false, true, false><<<dim3(32, 8), 512, 128 * 1024, stream>>>(
        attn_o, DMODEL, wo_t, DMODEL, bo, x, x1, DMODEL, DMODEL);

    // LN2
    ln_kernel<<<MROWS, 256, 0, stream>>>(x1, ln2g, ln2b, normed2);

    if (fullff) {
        // FF1 full-width -> hbuf [4096][4096] (128x256 tiles, 512 blocks)
        gemm128<true><<<dim3(32, 16), 512, 72 * 1024, stream>>>(
            normed2, DMODEL, w1_t, DMODEL, b1, hbuf, DFF, DMODEL);
        // FF2 single launch, K=4096, + residual -> out (f32, nontemporal)
        gemm4s<true, false, true, true><<<dim3(32, 8), 512, 128 * 1024, stream>>>(
            hbuf, DFF, w2_t, DFF, b2, x1, xout, DMODEL, DFF);
    } else {
        // FF halves (hbuf = 16MB)
        gemm128<true><<<dim3(32, 8), 512, 72 * 1024, stream>>>(
            normed2, DMODEL, w1_t, DMODEL, b1, hbuf, 2048, DMODEL);
        gemm4s<true, false, true, false><<<dim3(32, 8), 512, 128 * 1024, stream>>>(
            hbuf, 2048, w2_t, DFF, b2, x1, xout, DMODEL, 2048);
        gemm128<true><<<dim3(32, 8), 512, 72 * 1024, stream>>>(
            normed2, DMODEL, w1_t + 2048 * 1024, DMODEL, b1 + 2048, hbuf, 2048, DMODEL);
        gemm4s<true, false, true, true><<<dim3(32, 8), 512, 128 * 1024, stream>>>(
            hbuf, 2048, w2_t + 2048, DFF, bzero, xout, xout, DMODEL, 2048);
    }
}

// Round 16
// 312.319 us; speedup vs baseline: 1.0651x; 1.0077x over previous
//
#include <hip/hip_runtime.h>
#include <hip/hip_bf16.h>
#include <math.h>

#define DMODEL 1024
#define NSEQ   2048
#define NBATCH 2
#define NHEADS 16
#define DHEAD  64
#define DFF    4096
#define MROWS  (NBATCH*NSEQ)
#define QKVLD  3072   // fused qkv row stride

typedef __attribute__((ext_vector_type(8))) short bf16x8;
typedef __attribute__((ext_vector_type(4))) float f32x4;

static __device__ __forceinline__ ushort f2b(float f) {
    return __builtin_bit_cast(ushort, (__bf16)f);
}
static __device__ __forceinline__ float b2f(ushort u) {
    return (float)__builtin_bit_cast(__bf16, u);
}

static __device__ __forceinline__ f32x4 mfma16(bf16x8 a, bf16x8 b, f32x4 c) {
    return __builtin_amdgcn_mfma_f32_16x16x32_bf16(a, b, c, 0, 0, 0);
}

static __device__ __forceinline__ void gload_lds16(const void* g, void* lds) {
    __builtin_amdgcn_global_load_lds((const __attribute__((address_space(1))) void*)g,
                                     (__attribute__((address_space(3))) void*)lds,
                                     16, 0, 0);
}

// LDS-only barrier: does NOT drain vmcnt (global stores stay in flight).
static __device__ __forceinline__ void softbar() {
    __builtin_amdgcn_sched_barrier(0);
    asm volatile("s_waitcnt lgkmcnt(0)" ::: "memory");
    __builtin_amdgcn_s_barrier();
    __builtin_amdgcn_sched_barrier(0);
}

// ---------------- fused prep: 6 weight cast+transposes (LDS transpose) + bias concat + LN1 ----------------
static __device__ __forceinline__ void cast_tile_lds(const float* __restrict__ W,
                                                     ushort* __restrict__ Wt,
                                                     int K, int Nn, int bx, int by, int t,
                                                     float (*lds)[65])
{
    const int n0 = bx * 64;
    const int k0 = by * 64;
#pragma unroll
    for (int r = 0; r < 4; ++r) {
        const int kr = (t >> 4) + r * 16;
        const int nc = (t & 15) * 4;
        const float4 v = *(const float4*)(W + (long)(k0 + kr) * Nn + n0 + nc);
        lds[kr][nc] = v.x; lds[kr][nc + 1] = v.y; lds[kr][nc + 2] = v.z; lds[kr][nc + 3] = v.w;
    }
    __syncthreads();
    const int n  = t >> 2;            // 0..63 output row
    const int kc = (t & 3) * 16;      // 16 k per lane; 4 lanes cover 128B contiguous
    ushort tmp[16];
#pragma unroll
    for (int i = 0; i < 16; ++i) tmp[i] = f2b(lds[kc + i][n]);
    *(uint4*)(Wt + (long)(n0 + n) * K + k0 + kc)     = *(const uint4*)tmp;
    *(uint4*)(Wt + (long)(n0 + n) * K + k0 + kc + 8) = *(const uint4*)(tmp + 8);
}

__global__ __launch_bounds__(256) void prep(const float* __restrict__ wq,
                                            const float* __restrict__ wk,
                                            const float* __restrict__ wv,
                                            const float* __restrict__ wo,
                                            const float* __restrict__ w1,
                                            const float* __restrict__ w2,
                                            const float* __restrict__ bq,
                                            const float* __restrict__ bk,
                                            const float* __restrict__ bv,
                                            const float* __restrict__ x,
                                            const float* __restrict__ ln1g,
                                            const float* __restrict__ ln1b,
                                            ushort* __restrict__ wqkv_t,
                                            ushort* __restrict__ wo_t,
                                            ushort* __restrict__ w1_t,
                                            ushort* __restrict__ w2_t,
                                            float* __restrict__ bqkv,
                                            ushort* __restrict__ normed)
{
    __shared__ float red[4];
    __shared__ float tl[64][65];
    const int id  = blockIdx.x;
    const int tid = threadIdx.x;

    if (id < 256) {                       // wq: 16x16 tiles
        cast_tile_lds(wq, wqkv_t, 1024, 1024, id & 15, id >> 4, tid, tl);
    } else if (id < 512) {
        const int i2 = id - 256;
        cast_tile_lds(wk, wqkv_t + 1024 * 1024, 1024, 1024, i2 & 15, i2 >> 4, tid, tl);
    } else if (id < 768) {
        const int i2 = id - 512;
        cast_tile_lds(wv, wqkv_t + 2048 * 1024, 1024, 1024, i2 & 15, i2 >> 4, tid, tl);
    } else if (id < 1024) {
        const int i2 = id - 768;
        cast_tile_lds(wo, wo_t, 1024, 1024, i2 & 15, i2 >> 4, tid, tl);
    } else if (id < 2048) {               // w1: [1024][4096] -> Wt[4096][1024]
        const int i2 = id - 1024;
        cast_tile_lds(w1, w1_t, 1024, 4096, i2 & 63, i2 >> 6, tid, tl);
    } else if (id < 3072) {               // w2: [4096][1024] -> Wt[1024][4096]
        const int i2 = id - 2048;
        cast_tile_lds(w2, w2_t, 4096, 1024, i2 & 15, i2 >> 4, tid, tl);
    } else if (id < 3088) {
        const int t = (id - 3072) * 256 + tid;
        float v = 0.0f;
        if (t < 1024)      v = bq[t];
        else if (t < 2048) v = bk[t - 1024];
        else if (t < 3072) v = bv[t - 2048];
        bqkv[t] = v;
    } else {
        const int row = id - 3088;
        const float4 v = ((const float4*)(x + (long)row * DMODEL))[tid];
        float s = v.x + v.y + v.z + v.w;
#pragma unroll
        for (int o = 32; o; o >>= 1) s += __shfl_down(s, o, 64);
        if ((tid & 63) == 0) red[tid >> 6] = s;
        __syncthreads();
        const float mu = (red[0] + red[1] + red[2] + red[3]) * (1.0f / DMODEL);
        __syncthreads();
        const float d0 = v.x - mu, d1 = v.y - mu, d2 = v.z - mu, d3 = v.w - mu;
        float s2 = d0*d0 + d1*d1 + d2*d2 + d3*d3;
#pragma unroll
        for (int o = 32; o; o >>= 1) s2 += __shfl_down(s2, o, 64);
        if ((tid & 63) == 0) red[tid >> 6] = s2;
        __syncthreads();
        const float inv = rsqrtf((red[0] + red[1] + red[2] + red[3]) * (1.0f / DMODEL) + 1e-5f);
        const float4 gg = ((const float4*)ln1g)[tid];
        const float4 bv4 = ((const float4*)ln1b)[tid];
        ushort4 o4;
        o4.x = f2b(d0 * inv * gg.x + bv4.x);
        o4.y = f2b(d1 * inv * gg.y + bv4.y);
        o4.z = f2b(d2 * inv * gg.z + bv4.z);
        o4.w = f2b(d3 * inv * gg.w + bv4.w);
        ((ushort4*)(normed + (long)row * DMODEL))[tid] = o4;
    }
}

// ---------------- LayerNorm: templated input (f32 or bf16) -> bf16 out ----------------
template<bool INBF16>
__global__ __launch_bounds__(256) void ln_kernel(const void* __restrict__ xin,
                                                 const float* __restrict__ g,
                                                 const float* __restrict__ bb,
                                                 ushort* __restrict__ out)
{
    const int row = blockIdx.x;
    const int tid = threadIdx.x;
    float e0, e1, e2, e3;
    if (INBF16) {
        const ushort4 v4 = ((const ushort4*)((const ushort*)xin + (long)row * DMODEL))[tid];
        e0 = b2f(v4.x); e1 = b2f(v4.y); e2 = b2f(v4.z); e3 = b2f(v4.w);
    } else {
        const float4 v = ((const float4*)((const float*)xin + (long)row * DMODEL))[tid];
        e0 = v.x; e1 = v.y; e2 = v.z; e3 = v.w;
    }
    float s = e0 + e1 + e2 + e3;
#pragma unroll
    for (int o = 32; o; o >>= 1) s += __shfl_down(s, o, 64);
    __shared__ float red[4];
    if ((tid & 63) == 0) red[tid >> 6] = s;
    __syncthreads();
    const float mu = (red[0] + red[1] + red[2] + red[3]) * (1.0f / DMODEL);
    __syncthreads();
    const float d0 = e0 - mu, d1 = e1 - mu, d2 = e2 - mu, d3 = e3 - mu;
    float s2 = d0*d0 + d1*d1 + d2*d2 + d3*d3;
#pragma unroll
    for (int o = 32; o; o >>= 1) s2 += __shfl_down(s2, o, 64);
    if ((tid & 63) == 0) red[tid >> 6] = s2;
    __syncthreads();
    const float inv = rsqrtf((red[0] + red[1] + red[2] + red[3]) * (1.0f / DMODEL) + 1e-5f);
    const float4 gg = ((const float4*)g)[tid];
    const float4 bv = ((const float4*)bb)[tid];
    ushort4 o4;
    o4.x = f2b(d0 * inv * gg.x + bv.x);
    o4.y = f2b(d1 * inv * gg.y + bv.y);
    o4.z = f2b(d2 * inv * gg.z + bv.z);
    o4.w = f2b(d3 * inv * gg.w + bv.w);
    ((ushort4*)(out + (long)row * DMODEL))[tid] = o4;
}

// ---------------- deep-pipelined 128x256 GEMM, 8 waves, BK=32, 3 LDS buffers, depth-2 ----------------
template<bool GELU>
__global__ __launch_bounds__(512, 2) void gemm128(const ushort* __restrict__ A, int lda,
                                                  const ushort* __restrict__ Bt, int ldb,
                                                  const float* __restrict__ bias,
                                                  ushort* __restrict__ C, int ldc, int K)
{
    extern __shared__ char smem[];
    const int tid  = threadIdx.x;
    const int lane = tid & 63;
    const int w    = tid >> 6;
    const int wm   = w >> 2;                // 0..1  (M half, 64 rows each)
    const int wn   = w & 3;                 // 0..3  (N quarter)
    const long row0 = (long)blockIdx.x * 128;
    const long col0 = (long)blockIdx.y * 256;

    const int srow = tid >> 2;              // 0..127
    const int scol = (((tid & 3) ^ ((srow >> 1) & 3))) * 8;   // inverse-swizzled source slot
    const ushort* Ag = A  + (row0 + srow) * (long)lda + scol;
    const ushort* Bg = Bt + (col0 + srow) * (long)ldb + scol;

#define STAGE_A1(buf, k0)                                                                  \
    gload_lds16(Ag + (k0), smem + (buf) * 8192 + w * 1024)
#define STAGE_B1(buf, k0)                                                                  \
    do {                                                                                   \
        gload_lds16(Bg + (k0),                   smem + 24576 + (buf) * 16384 + w * 1024); \
        gload_lds16(Bg + 128 * (long)ldb + (k0), smem + 24576 + (buf) * 16384 + 8192 + w * 1024); \
    } while (0)

    const f32x4 zero = {0.f, 0.f, 0.f, 0.f};
    f32x4 acc[4][4];
#pragma unroll
    for (int m = 0; m < 4; ++m)
#pragma unroll
        for (int j = 0; j < 4; ++j) acc[m][j] = zero;

    const int NT = K >> 5;
    STAGE_A1(0, 0);  STAGE_B1(0, 0);
    STAGE_A1(1, 32); STAGE_B1(1, 32);

    const int mrow = lane & 15;
    const int xsl  = (((lane >> 4) ^ ((mrow >> 1) & 3))) * 8;  // swizzled read slot
    const int abase = (wm * 64 + mrow) * 32 + xsl;
    const int bbase = (wn * 64 + mrow) * 32 + xsl;

    for (int t = 0; t < NT; ++t) {
        if (t == NT - 1) asm volatile("s_waitcnt vmcnt(0)" ::: "memory");
        else             asm volatile("s_waitcnt vmcnt(3)" ::: "memory");
        __builtin_amdgcn_sched_barrier(0);
        __builtin_amdgcn_s_barrier();
        __builtin_amdgcn_sched_barrier(0);

        const int cb = t % 3;
        const ushort* Abase = (const ushort*)(smem + cb * 8192);
        const ushort* Bbase = (const ushort*)(smem + 24576 + cb * 16384);

        bf16x8 bfr[4], afr[2];
#pragma unroll
        for (int ni = 0; ni < 4; ++ni)
            bfr[ni] = *(const bf16x8*)&Bbase[bbase + ni * 512];
#pragma unroll
        for (int mi = 0; mi < 2; ++mi)
            afr[mi] = *(const bf16x8*)&Abase[abase + mi * 512];
        if (t + 2 < NT) STAGE_A1((t + 2) % 3, (t + 2) * 32);
        __builtin_amdgcn_s_setprio(1);
#pragma unroll
        for (int mi = 0; mi < 2; ++mi)
#pragma unroll
            for (int ni = 0; ni < 4; ++ni)
                acc[mi][ni] = mfma16(afr[mi], bfr[ni], acc[mi][ni]);
        __builtin_amdgcn_s_setprio(0);

#pragma unroll
        for (int mi = 0; mi < 2; ++mi)
            afr[mi] = *(const bf16x8*)&Abase[abase + (mi + 2) * 512];
        if (t + 2 < NT) STAGE_B1((t + 2) % 3, (t + 2) * 32);
        __builtin_amdgcn_s_setprio(1);
#pragma unroll
        for (int mi = 0; mi < 2; ++mi)
#pragma unroll
            for (int ni = 0; ni < 4; ++ni)
                acc[mi + 2][ni] = mfma16(afr[mi], bfr[ni], acc[mi + 2][ni]);
        __builtin_amdgcn_s_setprio(0);
    }
#undef STAGE_A1
#undef STAGE_B1

#pragma unroll
    for (int ni = 0; ni < 4; ++ni) {
        const int colg = (int)col0 + wn * 64 + ni * 16 + (lane & 15);
        const float bcol = bias[colg];
#pragma unroll
        for (int mi = 0; mi < 4; ++mi) {
#pragma unroll
            for (int r = 0; r < 4; ++r) {
                const long rowg = row0 + wm * 64 + mi * 16 + (lane >> 4) * 4 + r;
                float vv = acc[mi][ni][r] + bcol;
                if (GELU) vv = 0.5f * vv * (1.0f + erff(vv * 0.70710678118f));
                C[rowg * ldc + colg] = f2b(vv);
            }
        }
    }
}

// ---------------- split-K 128x128 GEMM: 8 waves = 2 K-groups x 4 waves, depth-3 pipeline ----------------
// RESHALF: residual input is bf16 (x1 stored bf16).
template<bool OUTF32, bool GELU, bool RES, bool NTST, bool RESHALF>
__global__ __launch_bounds__(512, 2) void gemm4s(const ushort* __restrict__ A, int lda,
                                                 const ushort* __restrict__ Bt, int ldb,
                                                 const float* __restrict__ bias,
                                                 const void* __restrict__ res,
                                                 void* __restrict__ Cout,
                                                 int Nn, int K)
{
    extern __shared__ char smem[];   // A: g*32KB + buf*8KB (64KB) | B: 64KB @ +65536
    const int tid  = threadIdx.x;
    const int lane = tid & 63;
    const int g    = tid >> 8;              // K-group
    const int tg   = tid & 255;             // thread-in-group
    const int w4   = tg >> 6;               // wave-in-group 0..3
    const int wm   = w4 >> 1, wn = w4 & 1;
    const long row0 = (long)blockIdx.x * 128;
    const long col0 = (long)blockIdx.y * 128;
    const int mrow = lane & 15;
    const int xsl  = (((lane >> 4) ^ ((mrow >> 1) & 3))) * 8;  // swizzled read slot

    const int srow = tg >> 2;               // 0..63
    const int soff = (((tg & 3) ^ ((srow >> 1) & 3))) * 8;     // inverse-swizzled source slot
    const int kb   = g * (K >> 1);          // group K origin
    const ushort* Ag = A  + (row0 + srow) * (long)lda + kb + soff;
    const ushort* Bg = Bt + (col0 + srow) * (long)ldb + kb + soff;
    char* Als = smem + g * 32768;
    char* Bls = smem + 65536 + g * 32768;

#define STAGE4S(buf, k0)                                                          \
    do {                                                                          \
        gload_lds16(Ag + (k0),                  Als + ((buf) << 13) + w4 * 1024); \
        gload_lds16(Ag + 64 * (long)lda + (k0), Als + ((buf) << 13) + 4096 + w4 * 1024); \
        gload_lds16(Bg + (k0),                  Bls + ((buf) << 13) + w4 * 1024); \
        gload_lds16(Bg + 64 * (long)ldb + (k0), Bls + ((buf) << 13) + 4096 + w4 * 1024); \
    } while (0)

    const f32x4 zero = {0.f, 0.f, 0.f, 0.f};
    f32x4 acc[4][4];
#pragma unroll
    for (int m = 0; m < 4; ++m)
#pragma unroll
        for (int j = 0; j < 4; ++j) acc[m][j] = zero;

    const int NT2 = K >> 6;                 // tiles per group
    STAGE4S(0, 0);
    STAGE4S(1, 32);
    STAGE4S(2, 64);

    const int abase = (wm * 64 + mrow) * 32 + xsl;
    const int bbase = (wn * 64 + mrow) * 32 + xsl;

    for (int t = 0; t < NT2; ++t) {
        if      (t >= NT2 - 1) asm volatile("s_waitcnt vmcnt(0)" ::: "memory");
        else if (t == NT2 - 2) asm volatile("s_waitcnt vmcnt(4)" ::: "memory");
        else                   asm volatile("s_waitcnt vmcnt(8)" ::: "memory");
        __builtin_amdgcn_sched_barrier(0);
        __builtin_amdgcn_s_barrier();
        __builtin_amdgcn_sched_barrier(0);

        if (t + 3 < NT2) STAGE4S((t + 3) & 3, (t + 3) * 32);

        const ushort* Abase = (const ushort*)(Als + ((t & 3) << 13));
        const ushort* Bbase = (const ushort*)(Bls + ((t & 3) << 13));
        bf16x8 af[4], bfv[4];
#pragma unroll
        for (int m = 0; m < 4; ++m)
            af[m] = *(const bf16x8*)&Abase[abase + m * 512];
#pragma unroll
        for (int j = 0; j < 4; ++j)
            bfv[j] = *(const bf16x8*)&Bbase[bbase + j * 512];
        __builtin_amdgcn_s_setprio(1);
#pragma unroll
        for (int m = 0; m < 4; ++m)
#pragma unroll
            for (int j = 0; j < 4; ++j)
                acc[m][j] = mfma16(af[m], bfv[j], acc[m][j]);
        __builtin_amdgcn_s_setprio(0);
    }
#undef STAGE4S

    // ---- cross-group reduce: g1 -> LDS ([elem][thread] layout, conflict-free), g0 combines ----
    __syncthreads();
    float* xch = (float*)smem;              // 64KB exchange region
    if (g == 1) {
#pragma unroll
        for (int m = 0; m < 4; ++m)
#pragma unroll
            for (int j = 0; j < 4; ++j)
#pragma unroll
                for (int r = 0; r < 4; ++r)
                    xch[(m * 16 + j * 4 + r) * 256 + tg] = acc[m][j][r];
    }
    __syncthreads();
    if (g == 0) {
#pragma unroll
        for (int j = 0; j < 4; ++j) {
            const int colg  = (int)col0 + wn * 64 + j * 16 + mrow;
            const float bcol = bias[colg];
#pragma unroll
            for (int m = 0; m < 4; ++m) {
#pragma unroll
                for (int r = 0; r < 4; ++r) {
                    const long rowg = row0 + wm * 64 + m * 16 + (lane >> 4) * 4 + r;
                    float vv = acc[m][j][r] + xch[(m * 16 + j * 4 + r) * 256 + tg] + bcol;
                    if (RES) {
                        if (RESHALF) vv += b2f(((const ushort*)res)[rowg * Nn + colg]);
                        else         vv += ((const float*)res)[rowg * Nn + colg];
                    }
                    if (GELU)  vv = 0.5f * vv * (1.0f + erff(vv * 0.70710678118f));
                    if (OUTF32) {
                        if (NTST) __builtin_nontemporal_store(vv, (float*)Cout + rowg * Nn + colg);
                        else      ((float*)Cout)[rowg * Nn + colg] = vv;
                    } else {
                        ((ushort*)Cout)[rowg * Nn + colg] = f2b(vv);
                    }
                }
            }
        }
    }
}

// ---------------- V transpose: v (= qkv + 2048, stride QKVLD) -> vt[B,H,DHEAD,N] ----------------
__global__ __launch_bounds__(256) void transpose_v(const ushort* __restrict__ v,
                                                   ushort* __restrict__ vt)
{
    __shared__ ushort t[64][72];
    const int nb = blockIdx.x, bh = blockIdx.y, b = bh >> 4;
    const int hcol = (bh & 15) * DHEAD;
    const int tid  = threadIdx.x;
    const int rrow = tid >> 3;          // 0..31
    const int cch  = (tid & 7) * 8;
#pragma unroll
    for (int r = 0; r < 2; ++r) {
        const int nr = rrow + r * 32;
        *(uint4*)&t[nr][cch] =
            *(const uint4*)(v + ((long)(b * NSEQ + nb * 64 + nr)) * QKVLD + hcol + cch);
    }
    __syncthreads();
#pragma unroll
    for (int r = 0; r < 2; ++r) {
        const int d = rrow + r * 32;
        ushort tmp[8];
#pragma unroll
        for (int i = 0; i < 8; ++i) tmp[i] = t[cch + i][d];
        *(uint4*)(vt + ((long)bh * DHEAD + d) * NSEQ + nb * 64 + cch) = *(const uint4*)tmp;
    }
}

// ---------------- fused sigmoid attention (QBLK=64, LDS-staged, softbar, XCD-swizzled) ----------------
__global__ __launch_bounds__(256) void attn_kernel(const ushort* __restrict__ qkv,
                                                   const ushort* __restrict__ vt,
                                                   float* __restrict__ probs,
                                                   ushort* __restrict__ ao)
{
    __shared__ ushort Ks[64][72];
    __shared__ ushort Vs[64][72];
    __shared__ __align__(16) float Pf[4][16][68];
    const int tid  = threadIdx.x;
    const int lane = tid & 63;
    const int w    = tid >> 6;
    const int lin  = blockIdx.x + 32 * blockIdx.y;
    const int xcd  = lin & 7;
    const int idx  = lin >> 3;
    const int bh   = xcd * 4 + (idx >> 5);
    const int qb   = idx & 31;
    const int b    = bh >> 4;
    const int q0   = qb * 64 + w * 16;
    const int mrow = lane & 15;
    const int kof  = (lane >> 4) * 8;
    const int hcol = (bh & 15) * DHEAD;
    const int NT   = NSEQ / 64;

    bf16x8 aq0, aq1;
    {
        const ushort* qp = qkv + ((long)(b * NSEQ + q0 + mrow)) * QKVLD + hcol;
        aq0 = *(const bf16x8*)(qp + kof);
        aq1 = *(const bf16x8*)(qp + 32 + kof);
    }

    const f32x4 zero = {0.f, 0.f, 0.f, 0.f};
    f32x4 acco[4];
#pragma unroll
    for (int dj = 0; dj < 4; ++dj) acco[dj] = zero;

    const int srow = tid >> 3;          // 0..31
    const int sch  = (tid & 7) * 8;
    const ushort* km = qkv + 1024;

    uint4 kr0, kr1, vr0, vr1;
#define LOADT(kt)                                                                          \
    do {                                                                                   \
        kr0 = *(const uint4*)(km + ((long)(b * NSEQ + (kt) * 64 + srow)) * QKVLD + hcol + sch);       \
        kr1 = *(const uint4*)(km + ((long)(b * NSEQ + (kt) * 64 + srow + 32)) * QKVLD + hcol + sch);  \
        vr0 = *(const uint4*)(vt + ((long)bh * DHEAD + srow) * NSEQ + (kt) * 64 + sch);               \
        vr1 = *(const uint4*)(vt + ((long)bh * DHEAD + srow + 32) * NSEQ + (kt) * 64 + sch);          \
    } while (0)

    LOADT(0);

    for (int kt = 0; kt < NT; ++kt) {
        *(uint4*)&Ks[srow][sch]      = kr0;
        *(uint4*)&Ks[srow + 32][sch] = kr1;
        *(uint4*)&Vs[srow][sch]      = vr0;
        *(uint4*)&Vs[srow + 32][sch] = vr1;
        softbar();                         // LDS visible; stores NOT drained
        if (kt + 1 < NT) LOADT(kt + 1);    // issued before this tile's probs stores

        f32x4 s[4];
#pragma unroll
        for (int j = 0; j < 4; ++j) s[j] = zero;
#pragma unroll
        for (int j = 0; j < 4; ++j) {
            bf16x8 b0 = *(const bf16x8*)&Ks[j * 16 + mrow][kof];
            bf16x8 b1 = *(const bf16x8*)&Ks[j * 16 + mrow][32 + kof];
            s[j] = mfma16(aq0, b0, s[j]);
            s[j] = mfma16(aq1, b1, s[j]);
        }

#pragma unroll
        for (int j = 0; j < 4; ++j) {
#pragma unroll
            for (int r = 0; r < 4; ++r) {
                const int rr = (lane >> 4) * 4 + r;
                const float e  = __expf(-0.125f * s[j][r]);
                const float pv = __builtin_amdgcn_rcpf(1.0f + e);
                Pf[w][rr][j * 16 + mrow] = pv;
            }
        }

        // vectorized nontemporal probs store: 4x dwordx4 per lane
        const long pbase = ((long)(bh * NSEQ + q0)) * NSEQ + kt * 64;
#pragma unroll
        for (int i = 0; i < 4; ++i) {
            const int rr = (lane >> 4) + 4 * i;
            const f32x4 pv4 = *(const f32x4*)&Pf[w][rr][mrow * 4];
            __builtin_nontemporal_store(pv4, (f32x4*)(probs + pbase + (long)rr * NSEQ + mrow * 4));
        }

        // PV: rebuild bf16 A-frag from f32 LDS tile
#pragma unroll
        for (int ks = 0; ks < 2; ++ks) {
            const f32x4 f0 = *(const f32x4*)&Pf[w][mrow][ks * 32 + kof];
            const f32x4 f1 = *(const f32x4*)&Pf[w][mrow][ks * 32 + kof + 4];
            bf16x8 ap;
            ap[0] = (short)f2b(f0[0]); ap[1] = (short)f2b(f0[1]);
            ap[2] = (short)f2b(f0[2]); ap[3] = (short)f2b(f0[3]);
            ap[4] = (short)f2b(f1[0]); ap[5] = (short)f2b(f1[1]);
            ap[6] = (short)f2b(f1[2]); ap[7] = (short)f2b(f1[3]);
#pragma unroll
            for (int dj = 0; dj < 4; ++dj) {
                bf16x8 bv = *(const bf16x8*)&Vs[dj * 16 + mrow][ks * 32 + kof];
                acco[dj] = mfma16(ap, bv, acco[dj]);
            }
        }
        softbar();                         // reads done; next tile may overwrite LDS
    }
#undef LOADT

    const float sc = rsqrtf((float)NSEQ);
#pragma unroll
    for (int dj = 0; dj < 4; ++dj)
#pragma unroll
        for (int r = 0; r < 4; ++r) {
            const int rr = (lane >> 4) * 4 + r;
            ao[((long)(b * NSEQ + q0 + rr)) * DMODEL + hcol + dj * 16 + mrow] =
                f2b(acco[dj][r] * sc);
        }
}

// ---------------- launch ----------------
extern "C" void kernel_launch(void* const* d_in, const int* in_sizes, int n_in,
                              void* d_out, int out_size, void* d_ws, size_t ws_size,
                              hipStream_t stream) {
    (void)in_sizes; (void)n_in; (void)out_size;
    const float* x    = (const float*)d_in[0];
    const float* wq   = (const float*)d_in[1];
    const float* bq   = (const float*)d_in[2];
    const float* wk   = (const float*)d_in[3];
    const float* bk   = (const float*)d_in[4];
    const float* wv   = (const float*)d_in[5];
    const float* bv   = (const float*)d_in[6];
    const float* wo   = (const float*)d_in[7];
    const float* bo   = (const float*)d_in[8];
    const float* ln1g = (const float*)d_in[9];
    const float* ln1b = (const float*)d_in[10];
    const float* ln2g = (const float*)d_in[11];
    const float* ln2b = (const float*)d_in[12];
    const float* w1   = (const float*)d_in[13];
    const float* b1   = (const float*)d_in[14];
    const float* w2   = (const float*)d_in[15];
    const float* b2   = (const float*)d_in[16];

    char* ws = (char*)d_ws;
    const size_t MB = 1u << 20;
    ushort* wqkv_t  = (ushort*)(ws + 0 * MB);    // [3072][1024] bf16, 6MB
    ushort* wo_t    = (ushort*)(ws + 6 * MB);    // [1024][1024], 2MB
    ushort* w1_t    = (ushort*)(ws + 8 * MB);    // [4096][1024], 8MB
    ushort* w2_t    = (ushort*)(ws + 16 * MB);   // [1024][4096], 8MB
    float*  bqkv    = (float*) (ws + 24 * MB);   // 3072 + 1024 zeros
    ushort* normed  = (ushort*)(ws + 25 * MB);   // [4096][1024], 8MB
    ushort* qkvbuf  = (ushort*)(ws + 33 * MB);   // [4096][3072], 24MB
    ushort* vtb     = (ushort*)(ws + 57 * MB);   // [32][64][2048], 8MB
    ushort* attn_o  = (ushort*)(ws + 65 * MB);   // [4096][1024], 8MB
    ushort* x1b     = (ushort*)(ws + 41 * MB);   // [4096][1024] bf16, 8MB (aliases dead qkvbuf tail)
    ushort* normed2 = (ushort*)(ws + 25 * MB);   // aliases normed (dead)
    ushort* hbuf    = (ushort*)(ws + 57 * MB);   // halves: [4096][2048] 16MB; full: [4096][4096] 32MB
    const float* bzero = bqkv + 3072;
    const bool fullff = (ws_size >= 89 * MB);

    float* xout  = (float*)d_out;
    float* probs = xout + (size_t)MROWS * DMODEL;

    // fused prep: all weight casts (LDS transpose) + bias concat + LN1 (one launch)
    prep<<<7184, 256, 0, stream>>>(wq, wk, wv, wo, w1, w2, bq, bk, bv,
                                   x, ln1g, ln1b,
                                   wqkv_t, wo_t, w1_t, w2_t, bqkv, normed);

    // fused QKV projection: [4096,1024] @ [1024,3072] -> qkvbuf (128x256 tiles, 384 blocks)
    gemm128<false><<<dim3(32, 12), 512, 72 * 1024, stream>>>(
        normed, DMODEL, wqkv_t, DMODEL, bqkv, qkvbuf, QKVLD, DMODEL);

    // V -> V^T per head
    transpose_v<<<dim3(NSEQ / 64, NBATCH * NHEADS), 256, 0, stream>>>(qkvbuf + 2048, vtb);

    // fused sigmoid attention (writes probs + attn_out/sqrt(N)), XCD-swizzled
    attn_kernel<<<dim3(NSEQ / 64, NBATCH * NHEADS), 256, 0, stream>>>(
        qkvbuf, vtb, probs, attn_o);

    // out projection + residual (x, f32) -> x1b (bf16), split-K deep pipeline
    gemm4s<false, false, true, false, false><<<dim3(32, 8), 512, 128 * 1024, stream>>>(
        attn_o, DMODEL, wo_t, DMODEL, bo, x, x1b, DMODEL, DMODEL);

    // LN2 (bf16 input)
    ln_kernel<true><<<MROWS, 256, 0, stream>>>(x1b, ln2g, ln2b, normed2);

    if (fullff) {
        // FF1 full-width -> hbuf [4096][4096] (128x256 tiles, 512 blocks)
        gemm128<true><<<dim3(32, 16), 512, 72 * 1024, stream>>>(
            normed2, DMODEL, w1_t, DMODEL, b1, hbuf, DFF, DMODEL);
        // FF2 single launch, K=4096, + residual (x1b, bf16) -> out (f32, nontemporal)
        gemm4s<true, false, true, true, true><<<dim3(32, 8), 512, 128 * 1024, stream>>>(
            hbuf, DFF, w2_t, DFF, b2, x1b, xout, DMODEL, DFF);
    } else {
        // FF halves (hbuf = 16MB)
        gemm128<true><<<dim3(32, 8), 512, 72 * 1024, stream>>>(
            normed2, DMODEL, w1_t, DMODEL, b1, hbuf, 2048, DMODEL);
        gemm4s<true, false, true, false, true><<<dim3(32, 8), 512, 128 * 1024, stream>>>(
            hbuf, 2048, w2_t, DFF, b2, x1b, xout, DMODEL, 2048);
        gemm128<true><<<dim3(32, 8), 512, 72 * 1024, stream>>>(
            normed2, DMODEL, w1_t + 2048 * 1024, DMODEL, b1 + 2048, hbuf, 2048, DMODEL);
        gemm4s<true, false, true, true, false><<<dim3(32, 8), 512, 128 * 1024, stream>>>(
            hbuf, 2048, w2_t + 2048, DFF, bzero, xout, xout, DMODEL, 2048);
    }
}